// Round 16
// baseline (2309.154 us; speedup 1.0000x reference)
//
#include <hip/hip_runtime.h>

typedef __bf16 bf16x8 __attribute__((ext_vector_type(8)));
typedef float  f32x4  __attribute__((ext_vector_type(4)));

#define E_EDGES 100000
#define N_NODES 25000
#define N_GRAPHS 2048
#define HID 512
#define CAP 32

__device__ __forceinline__ void gload_lds16(const void* g, void* l) {
    __builtin_amdgcn_global_load_lds(
        (const __attribute__((address_space(1))) void*)g,
        (__attribute__((address_space(3))) void*)l, 16, 0, 0);
}

__device__ __forceinline__ __bf16 rtne(float x) {
    union { unsigned short s; __bf16 b; } u;
    unsigned v = __float_as_uint(x);
    u.s = (unsigned short)((v + 0x7FFF + ((v >> 16) & 1)) >> 16);
    return u.b;
}

__device__ __forceinline__ void split2(float x, __bf16& hi, __bf16& lo) {
    hi = rtne(x);
    lo = rtne(x - (float)hi);
}

__device__ __forceinline__ float ldf(const void* p, long i, int f32) {
    return f32 ? ((const float*)p)[i] : (float)(((const __bf16*)p)[i]);
}

// flags[0]=1 if float inputs are f32 (else bf16); flags[1]=1 if int inputs are i64
__global__ void probe_dtypes(const unsigned* __restrict__ xr, const unsigned* __restrict__ eir,
                             int* __restrict__ flags)
{
    __shared__ int cfp, ci;
    if (threadIdx.x == 0) { cfp = 0; ci = 0; }
    __syncthreads();
    int lc = 0;
    for (int i = threadIdx.x; i < 1024; i += 256) {
        unsigned elo = (xr[i] >> 7) & 0xFFu;
        if (elo > 140u) lc++;
    }
    atomicAdd(&cfp, lc);
    int ln = 0;
    for (int i = threadIdx.x; i < 512; i += 256) {
        if (eir[2 * i + 1] != 0u) ln++;
    }
    atomicAdd(&ci, ln);
    __syncthreads();
    if (threadIdx.x == 0) {
        flags[0] = (cfp > 100) ? 1 : 0;
        flags[1] = (ci < 256) ? 1 : 0;
    }
}

__global__ void to_int32(const void* __restrict__ src, int* __restrict__ dst, long n,
                         const int* __restrict__ flags)
{
    long i = (long)blockIdx.x * 256 + threadIdx.x;
    if (i >= n) return;
    dst[i] = flags[1] ? (int)((const long long*)src)[i] : ((const int*)src)[i];
}

// Tiled transpose+split: WThi/WTlo[n,k] = split(W[krow0+k, n]), zero-pad to Kpad.
__global__ __launch_bounds__(256) void split_transpose_t(
    const void* __restrict__ W, __bf16* __restrict__ Whi, __bf16* __restrict__ Wlo,
    int Ksrc, int N, int Kpad, int krow0, const int* __restrict__ flags)
{
    __shared__ float tile[64][65];
    const int nb = blockIdx.x * 64;
    const int kb = blockIdx.y * 64;
    const int f32m = flags[0];
    const int lx = threadIdx.x & 63;

    for (int rr = threadIdx.x >> 6; rr < 64; rr += 4) {
        const int k = kb + rr;
        const int n = nb + lx;
        float v = 0.f;
        if (k < Ksrc && n < N) v = ldf(W, (size_t)(krow0 + k) * N + n, f32m);
        tile[rr][lx] = v;
    }
    __syncthreads();
    for (int rr = threadIdx.x >> 6; rr < 64; rr += 4) {
        const int n = nb + rr;
        const int k = kb + lx;
        if (n < N && k < Kpad) {
            __bf16 hi, lo; split2(tile[lx][rr], hi, lo);
            Whi[(size_t)n * Kpad + k] = hi;
            Wlo[(size_t)n * Kpad + k] = lo;
        }
    }
}

// A_init[e,0:160] = [x[row[e],0:133], ea[e,0:14], 0] -> hi/lo; one thread per 8-f chunk
__global__ void build_Ainit_split8(const void* __restrict__ x, const void* __restrict__ ea,
                                   const int* __restrict__ row, __bf16* __restrict__ Ah,
                                   __bf16* __restrict__ Al, const int* __restrict__ flags)
{
    long idx = (long)blockIdx.x * 256 + threadIdx.x;
    if (idx >= (long)E_EDGES * 20) return;
    const int e = (int)(idx / 20), c = (int)(idx % 20);
    const int f0 = c * 8;
    const int f32m = flags[0];
    const int r = row[e];
    bf16x8 oh, ol;
    #pragma unroll
    for (int j = 0; j < 8; ++j) {
        const int f = f0 + j;
        float v = 0.f;
        if (f < 133)      v = ldf(x, (size_t)r * 133 + f, f32m);
        else if (f < 147) v = ldf(ea, (size_t)e * 14 + (f - 133), f32m);
        __bf16 hi, lo; split2(v, hi, lo);
        oh[j] = hi; ol[j] = lo;
    }
    *(bf16x8*)(Ah + (size_t)e * 160 + f0) = oh;
    *(bf16x8*)(Al + (size_t)e * 160 + f0) = ol;
}

// A_e2n[n,0:672] = [x[n,0:133], s_f32[n,0:512], 0] -> hi/lo; one thread per 8-f chunk
__global__ void build_Ae2n_split8(const void* __restrict__ x, const float* __restrict__ s,
                                  __bf16* __restrict__ Ah, __bf16* __restrict__ Al,
                                  const int* __restrict__ flags)
{
    long idx = (long)blockIdx.x * 256 + threadIdx.x;
    if (idx >= (long)N_NODES * 84) return;
    const int n = (int)(idx / 84), c = (int)(idx % 84);
    const int f0 = c * 8;
    const int f32m = flags[0];
    bf16x8 oh, ol;
    #pragma unroll
    for (int j = 0; j < 8; ++j) {
        const int f = f0 + j;
        float v = 0.f;
        if (f < 133)      v = ldf(x, (size_t)n * 133 + f, f32m);
        else if (f < 645) v = s[(size_t)n * HID + (f - 133)];
        __bf16 hi, lo; split2(v, hi, lo);
        oh[j] = hi; ol[j] = lo;
    }
    *(bf16x8*)(Ah + (size_t)n * 672 + f0) = oh;
    *(bf16x8*)(Al + (size_t)n * 672 + f0) = ol;
}

// Wide split-precision GEMM: C[M,512] = relu(A @ BT^T + bias), 3-term MFMA.
__global__ __launch_bounds__(1024) void gemm3w(
    const __bf16* __restrict__ Ah, const __bf16* __restrict__ Al,
    const __bf16* __restrict__ Bh, const __bf16* __restrict__ Bl,
    const void* __restrict__ bias,
    void* __restrict__ C, int out_f32, int kmaj, int M, int K, const int* __restrict__ flags)
{
    __shared__ __bf16 lAh[128 * 32];
    __shared__ __bf16 lAl[128 * 32];
    __shared__ __bf16 lBh[512 * 32];

    const int m0 = blockIdx.x * 128;
    const int tid = threadIdx.x;
    const int w = tid >> 6;
    const int lane = tid & 63;

    const int ac = tid & 511;
    int arow = m0 + (ac >> 2); if (arow >= M) arow = M - 1;
    const int akc = (ac & 3) << 3;
    const __bf16* Asrc = (tid < 512) ? Ah : Al;
    const size_t ag = (size_t)arow * K + akc;
    __bf16* aw = ((tid < 512) ? lAh : lAl) + (ac >> 2) * 32 + akc;

    const size_t bg0 = (size_t)(tid >> 2) * K + ((tid & 3) << 3);
    const size_t bg1 = (size_t)((tid + 1024) >> 2) * K + (((tid + 1024) & 3) << 3);
    __bf16* wB0 = lBh + (size_t)tid * 8;
    __bf16* wB1 = lBh + (size_t)(tid + 1024) * 8;

    const int mh = (w >> 3) * 64;
    const int nq = (w & 7) * 64;
    const int c16 = lane & 15;
    const int quad = lane >> 4;

    const __bf16* blp = Bl + (size_t)(nq + c16) * K + quad * 8;

    f32x4 acc[4][4] = {};

    for (int k0 = 0; k0 < K; k0 += 32) {
        gload_lds16(Asrc + ag + k0, aw);
        gload_lds16(Bh + bg0 + k0, wB0);
        gload_lds16(Bh + bg1 + k0, wB1);
        __syncthreads();

        bf16x8 bl[4];
        #pragma unroll
        for (int j = 0; j < 4; ++j)
            bl[j] = *(const bf16x8*)(blp + (size_t)(j * 16) * K + k0);

        bf16x8 ah[4], al[4];
        #pragma unroll
        for (int i = 0; i < 4; ++i) {
            ah[i] = *(const bf16x8*)(lAh + (mh + i * 16 + c16) * 32 + quad * 8);
            al[i] = *(const bf16x8*)(lAl + (mh + i * 16 + c16) * 32 + quad * 8);
        }
        #pragma unroll
        for (int j = 0; j < 4; ++j) {
            bf16x8 bh = *(const bf16x8*)(lBh + (nq + j * 16 + c16) * 32 + quad * 8);
            #pragma unroll
            for (int i = 0; i < 4; ++i) {
                acc[i][j] = __builtin_amdgcn_mfma_f32_16x16x32_bf16(ah[i], bh, acc[i][j], 0, 0, 0);
                acc[i][j] = __builtin_amdgcn_mfma_f32_16x16x32_bf16(al[i], bh, acc[i][j], 0, 0, 0);
                acc[i][j] = __builtin_amdgcn_mfma_f32_16x16x32_bf16(ah[i], bl[j], acc[i][j], 0, 0, 0);
            }
        }
        __syncthreads();
    }

    const int f32 = flags[0];
    const size_t kstride = (size_t)M * 32;
    #pragma unroll
    for (int j = 0; j < 4; ++j) {
        const int gcol = nq + j * 16 + c16;
        const float bv = ldf(bias, gcol, f32);
        #pragma unroll
        for (int i = 0; i < 4; ++i) {
            const int growb = m0 + mh + i * 16 + quad * 4;
            #pragma unroll
            for (int rr = 0; rr < 4; ++rr) {
                const int grow = growb + rr;
                if (grow < M) {
                    float v = acc[i][j][rr] + bv;
                    v = v > 0.f ? v : 0.f;
                    if (out_f32)   ((float*)C)[(size_t)grow * HID + gcol] = v;
                    else if (kmaj) ((__bf16*)C)[(size_t)(gcol >> 5) * kstride + (size_t)grow * 32 + (gcol & 31)] = rtne(v);
                    else           ((__bf16*)C)[(size_t)grow * HID + gcol] = rtne(v);
                }
            }
        }
    }
}

// DMPNN conv v6: BK=64 (halved barrier count vs r12; LDS 80KB, still 2 blocks/CU
// since 16-wave blocks are wave-limited anyway). 2-term mh@(Bh+Bl), in-place capable,
// k-major h [16][M][32]. ks-inner loop preserves exact accumulation order.
__global__ __launch_bounds__(1024) void conv3(
    const __bf16* __restrict__ abuf, const __bf16* hsrc,
    const int* __restrict__ row, const __bf16* __restrict__ Bh,
    const __bf16* __restrict__ Bl, const void* __restrict__ bias, int bias_off,
    const __bf16* __restrict__ res, __bf16* hdst, int M, const int* __restrict__ flags)
{
    __shared__ __bf16 lAh[128 * 64];   // 16KB
    __shared__ __bf16 lBh[512 * 64];   // 64KB

    const int m0 = blockIdx.x * 128;
    const int tid = threadIdx.x;
    const int w = tid >> 6;        // 0..15
    const int lane = tid & 63;
    const size_t kstride = (size_t)M * 32;

    // --- A staging: ALL 1024 threads, one chunk each: row tid>>3, k-chunk (tid&7)*8 ---
    const int arow = tid >> 3;
    const int kloc = (tid & 7) << 3;    // 0..56
    int e = m0 + arow; if (e >= M) e = M - 1;
    const int rn = row[e];
    const int vv = e ^ 1;
    const __bf16* ap = abuf + (size_t)rn * HID + kloc;                    // + k0
    const int ksl = kloc >> 5;          // slice parity of this chunk (0/1)
    const int kin = kloc & 31;
    const __bf16* hp = hsrc + (size_t)ksl * kstride + (size_t)vv * 32 + kin;  // + kb0*kstride
    __bf16* wAh = lAh + arow * 64 + kloc;

    // --- Bh staging: 4096 chunks; thread stages chunks tid + q*1024, q=0..3 ---
    // chunk c: row c>>3, k-chunk (c&7)*8
    size_t bgo[4]; __bf16* wBo[4];
    #pragma unroll
    for (int q = 0; q < 4; ++q) {
        const int c = tid + q * 1024;
        bgo[q] = (size_t)(c >> 3) * HID + ((c & 7) << 3);
        wBo[q] = lBh + (size_t)c * 8;
    }

    const int mh = (w >> 3) * 64;   // 0 / 64
    const int nq = (w & 7) * 64;    // 0..448
    const int c16 = lane & 15;
    const int quad = lane >> 4;

    const __bf16* blp = Bl + (size_t)(nq + c16) * HID + quad * 8;

    f32x4 acc[4][4] = {};

    bf16x8 av = *(const bf16x8*)(ap);
    bf16x8 hv = *(const bf16x8*)(hp);

    for (int it = 0; it < 8; ++it) {
        const int k0 = it * 64;
        // write phase: message chunk + Bh DMA
        {
            bf16x8 mh8;
            #pragma unroll
            for (int j = 0; j < 8; ++j)
                mh8[j] = rtne((float)av[j] - (float)hv[j]);
            *(bf16x8*)wAh = mh8;
        }
        #pragma unroll
        for (int q = 0; q < 4; ++q)
            gload_lds16(Bh + bgo[q] + k0, wBo[q]);
        // prefetch next iteration's A operands
        if (it < 7) {
            av = *(const bf16x8*)(ap + k0 + 64);
            hv = *(const bf16x8*)(hp + (size_t)(2 * it + 2) * kstride);
        }
        __syncthreads();

        // compute: two 32-slices, exact same accumulation order as BK=32 version
        #pragma unroll
        for (int ks = 0; ks < 2; ++ks) {
            bf16x8 bl[4];
            #pragma unroll
            for (int j = 0; j < 4; ++j)
                bl[j] = *(const bf16x8*)(blp + (size_t)(j * 16) * HID + k0 + ks * 32);

            bf16x8 ah[4];
            #pragma unroll
            for (int i = 0; i < 4; ++i)
                ah[i] = *(const bf16x8*)(lAh + (mh + i * 16 + c16) * 64 + ks * 32 + quad * 8);

            #pragma unroll
            for (int j = 0; j < 4; ++j) {
                bf16x8 bh = *(const bf16x8*)(lBh + (nq + j * 16 + c16) * 64 + ks * 32 + quad * 8);
                #pragma unroll
                for (int i = 0; i < 4; ++i) {
                    acc[i][j] = __builtin_amdgcn_mfma_f32_16x16x32_bf16(ah[i], bh, acc[i][j], 0, 0, 0);
                    acc[i][j] = __builtin_amdgcn_mfma_f32_16x16x32_bf16(ah[i], bl[j], acc[i][j], 0, 0, 0);
                }
            }
        }
        __syncthreads();
    }

    const int f32 = flags[0];
    #pragma unroll
    for (int j = 0; j < 4; ++j) {
        const int gcol = nq + j * 16 + c16;
        const float bv = ldf(bias, bias_off + gcol, f32);
        const size_t cb = (size_t)(gcol >> 5) * kstride + (gcol & 31);
        #pragma unroll
        for (int i = 0; i < 4; ++i) {
            const int growb = m0 + mh + i * 16 + quad * 4;
            #pragma unroll
            for (int rr = 0; rr < 4; ++rr) {
                const int grow = growb + rr;
                if (grow < M) {
                    const size_t idx = cb + (size_t)grow * 32;
                    float vcur = acc[i][j][rr] + bv + (float)res[idx];
                    vcur = vcur > 0.f ? vcur : 0.f;
                    hdst[idx] = rtne(vcur);
                }
            }
        }
    }
}

__global__ void bucket_build(const int* __restrict__ col, int* __restrict__ counts,
                             int* __restrict__ buckets, int E)
{
    int e = blockIdx.x * 256 + threadIdx.x;
    if (e >= E) return;
    int c = col[e];
    int p = atomicAdd(&counts[c], 1);
    if (p < CAP) buckets[(size_t)c * CAP + p] = e;
}

// Vectorized segsum: one thread per (node, 8-feature chunk); h K-MAJOR [16][E][32].
__global__ __launch_bounds__(256) void segsum8(
    const __bf16* __restrict__ h, const int* __restrict__ counts,
    const int* __restrict__ buckets, __bf16* __restrict__ abf,
    float* __restrict__ af32)
{
    const int nid = blockIdx.x * 4 + (threadIdx.x >> 6);
    const int fc = threadIdx.x & 63;
    if (nid >= N_NODES) return;
    const int kb = fc >> 2;
    const int off = (fc & 3) << 3;
    const size_t base = (size_t)kb * ((size_t)E_EDGES * 32) + off;
    int cnt = counts[nid]; if (cnt > CAP) cnt = CAP;
    const int* bl = buckets + (size_t)nid * CAP;
    float s[8] = {0.f, 0.f, 0.f, 0.f, 0.f, 0.f, 0.f, 0.f};
    for (int i = 0; i < cnt; ++i) {
        const int e = bl[i];
        bf16x8 v = *(const bf16x8*)(h + base + (size_t)e * 32);
        #pragma unroll
        for (int j = 0; j < 8; ++j) s[j] += (float)v[j];
    }
    if (af32) {
        f32x4* out = (f32x4*)(af32 + (size_t)nid * HID + fc * 8);
        out[0] = f32x4{s[0], s[1], s[2], s[3]};
        out[1] = f32x4{s[4], s[5], s[6], s[7]};
    } else {
        bf16x8 o;
        #pragma unroll
        for (int j = 0; j < 8; ++j) o[j] = rtne(s[j]);
        *(bf16x8*)(abf + (size_t)nid * HID + fc * 8) = o;
    }
}

__global__ void graph_starts(const int* __restrict__ batch, int* __restrict__ gstart, int N, int G)
{
    int n = blockIdx.x * 256 + threadIdx.x;
    if (n >= N) return;
    int b = batch[n];
    if (n == 0) {
        for (int g = 0; g <= b; ++g) gstart[g] = 0;
    } else {
        int pb = batch[n - 1];
        for (int g = pb + 1; g <= b; ++g) gstart[g] = n;
    }
    if (n == N - 1) {
        for (int g = b + 1; g <= G; ++g) gstart[g] = N;
    }
}

__global__ void pool_nodes(const float* __restrict__ hn, const int* __restrict__ gstart,
                           float* __restrict__ Apool)
{
    int g = blockIdx.x;
    int s = gstart[g], e = gstart[g + 1];
    for (int f = threadIdx.x; f < HID; f += 256) {
        float acc = 0.f;
        for (int n = s; n < e; ++n) acc += hn[(size_t)n * HID + f];
        Apool[(size_t)g * HID + f] = acc;
    }
}

// fused ffn: per block 8 graphs; t = relu(Apool@W1+b1); out = t@W2 + b2 (all f32)
__global__ __launch_bounds__(256) void ffn_fused(
    const float* __restrict__ Apool, const void* __restrict__ W1,
    const void* __restrict__ b1, const void* __restrict__ W2,
    const void* __restrict__ b2v, void* __restrict__ outv,
    const int* __restrict__ flags)
{
    __shared__ float sA[8][512];
    __shared__ float t[8][512];
    __shared__ float sW2[512];
    __shared__ float red[4];
    const int tid = threadIdx.x;
    const int g0 = blockIdx.x * 8;
    const int f32 = flags[0];

    for (int i = tid; i < 4096; i += 256)
        sA[i >> 9][i & 511] = Apool[(size_t)g0 * 512 + i];
    for (int n = tid; n < 512; n += 256)
        sW2[n] = ldf(W2, n, f32);
    __syncthreads();

    {
        float acc0[8], acc1[8];
        const float bb0 = ldf(b1, tid, f32);
        const float bb1 = ldf(b1, tid + 256, f32);
        #pragma unroll
        for (int gi = 0; gi < 8; ++gi) { acc0[gi] = bb0; acc1[gi] = bb1; }
        if (f32) {
            const float* Wf = (const float*)W1;
            for (int k = 0; k < 512; ++k) {
                float w0 = Wf[(size_t)k * 512 + tid];
                float w1 = Wf[(size_t)k * 512 + tid + 256];
                #pragma unroll
                for (int gi = 0; gi < 8; ++gi) {
                    float a = sA[gi][k];
                    acc0[gi] += a * w0;
                    acc1[gi] += a * w1;
                }
            }
        } else {
            const __bf16* Wb = (const __bf16*)W1;
            for (int k = 0; k < 512; ++k) {
                float w0 = (float)Wb[(size_t)k * 512 + tid];
                float w1 = (float)Wb[(size_t)k * 512 + tid + 256];
                #pragma unroll
                for (int gi = 0; gi < 8; ++gi) {
                    float a = sA[gi][k];
                    acc0[gi] += a * w0;
                    acc1[gi] += a * w1;
                }
            }
        }
        #pragma unroll
        for (int gi = 0; gi < 8; ++gi) {
            t[gi][tid]       = acc0[gi] > 0.f ? acc0[gi] : 0.f;
            t[gi][tid + 256] = acc1[gi] > 0.f ? acc1[gi] : 0.f;
        }
    }
    __syncthreads();

    const int lane = tid & 63;
    const int w = tid >> 6;
    const float b2 = ldf(b2v, 0, f32);
    for (int gi = 0; gi < 8; ++gi) {
        float p = t[gi][tid] * sW2[tid] + t[gi][tid + 256] * sW2[tid + 256];
        for (int o = 32; o; o >>= 1) p += __shfl_down(p, o, 64);
        if (lane == 0) red[w] = p;
        __syncthreads();
        if (tid == 0) {
            float r = red[0] + red[1] + red[2] + red[3] + b2;
            if (f32) ((float*)outv)[g0 + gi] = r;
            else     ((__bf16*)outv)[g0 + gi] = rtne(r);
        }
        __syncthreads();
    }
}

extern "C" void kernel_launch(void* const* d_in, const int* in_sizes, int n_in,
                              void* d_out, int out_size, void* d_ws, size_t ws_size,
                              hipStream_t stream)
{
    const int E = E_EDGES, NN = N_NODES, G = N_GRAPHS;

    char* wsp = (char*)d_ws;
    size_t off = 0;
    auto carve = [&](size_t bytes) -> void* {
        void* p = wsp + off;
        off += (bytes + 511) & ~(size_t)511;
        return p;
    };

    __bf16* h0    = (__bf16*)carve((size_t)E * HID * 2);   // k-major [16][E][32]
    __bf16* h     = (__bf16*)carve((size_t)E * HID * 2);   // k-major (also Ainit/Ae2n scratch)
    __bf16* abuf  = (__bf16*)carve((size_t)NN * HID * 2);  // row-major
    float*  Apool = (float*) carve((size_t)G * HID * 4);
    __bf16* WTih  = (__bf16*)carve((size_t)512 * 160 * 2);
    __bf16* WTil  = (__bf16*)carve((size_t)512 * 160 * 2);
    __bf16* WTch  = (__bf16*)carve((size_t)4 * 512 * 512 * 2);
    __bf16* WTcl  = (__bf16*)carve((size_t)4 * 512 * 512 * 2);
    __bf16* WTqh  = (__bf16*)carve((size_t)512 * 672 * 2);
    __bf16* WTql  = (__bf16*)carve((size_t)512 * 672 * 2);
    int*    ei32  = (int*)   carve((size_t)2 * E * 4);
    int*    b32   = (int*)   carve((size_t)NN * 4);
    int*    counts= (int*)   carve((size_t)NN * 4);
    int*    bucket= (int*)   carve((size_t)NN * CAP * 4);
    int*    gstart= (int*)   carve((size_t)(G + 1) * 4);
    int*    flags = (int*)   carve(2 * 4);

    // aliases into provably-dead regions
    __bf16* Aih = h;                              // E*160 bf16 (32 MB)
    __bf16* Ail = h + (size_t)E * 160;            // 32 MB; h dead until conv layer-1 output
    __bf16* Aqh = h;                              // NN*672 (33.6 MB)
    __bf16* Aql = h + (size_t)NN * 672;           // h dead after final segsum
    float*  hn   = (float*)h0;                    // NN*512 f32; h0 dead after conv4
    float*  sfin = (float*)((char*)h0 + (size_t)NN * HID * 4);  // NN*512 f32 (row-major)

    if (off > ws_size) {  // clean fail instead of faulting
        hipMemsetAsync(d_out, 0, (size_t)out_size * 4, stream);
        return;
    }

    auto cdiv = [](long a, long b) { return (int)((a + b - 1) / b); };

    probe_dtypes<<<1, 256, 0, stream>>>((const unsigned*)d_in[0], (const unsigned*)d_in[1], flags);
    to_int32<<<cdiv((long)2 * E, 256), 256, 0, stream>>>(d_in[1], ei32, (long)2 * E, flags);
    to_int32<<<cdiv(NN, 256), 256, 0, stream>>>(d_in[3], b32, NN, flags);

    const int* row = ei32;
    const int* col = ei32 + E;

    hipMemsetAsync(counts, 0, (size_t)NN * 4, stream);

    split_transpose_t<<<dim3(8, 3), 256, 0, stream>>>(d_in[4], WTih, WTil, 147, 512, 160, 0, flags);
    for (int l = 0; l < 4; ++l)
        split_transpose_t<<<dim3(8, 8), 256, 0, stream>>>(
            d_in[6], WTch + (size_t)l * 512 * 512, WTcl + (size_t)l * 512 * 512,
            512, 512, 512, l * 512, flags);
    split_transpose_t<<<dim3(8, 11), 256, 0, stream>>>(d_in[8], WTqh, WTql, 645, 512, 672, 0, flags);

    bucket_build<<<cdiv(E, 256), 256, 0, stream>>>(col, counts, bucket, E);

    // edge init: h0 = relu([x[row], ea] @ W_ei + b_ei) -> k-major  (wide 3-term GEMM)
    build_Ainit_split8<<<cdiv((long)E * 20, 256), 256, 0, stream>>>(d_in[0], d_in[2], row, Aih, Ail, flags);
    gemm3w<<<cdiv(E, 128), 1024, 0, stream>>>(Aih, Ail, WTih, WTil, d_in[5], h0, 0, 1, E, 160, flags);

    // DMPNN layers (layer 1: h0 -> h; layers 2-4 in-place h -> h), all k-major
    const __bf16* hcur = h0;
    for (int l = 0; l < 4; ++l) {
        segsum8<<<cdiv(NN, 4), 256, 0, stream>>>(hcur, counts, bucket, abuf, nullptr);
        conv3<<<cdiv(E, 128), 1024, 0, stream>>>(
            abuf, hcur, row, WTch + (size_t)l * 512 * 512, WTcl + (size_t)l * 512 * 512,
            d_in[7], l * 512, h0, h, E, flags);
        hcur = h;
    }

    // final aggregation (f32, row-major out) + e2n (wide 3-term GEMM, f32 row-major out)
    segsum8<<<cdiv(NN, 4), 256, 0, stream>>>(hcur, counts, bucket, nullptr, sfin);
    build_Ae2n_split8<<<cdiv((long)NN * 84, 256), 256, 0, stream>>>(d_in[0], sfin, Aqh, Aql, flags);
    gemm3w<<<cdiv(NN, 128), 1024, 0, stream>>>(Aqh, Aql, WTqh, WTql, d_in[9], hn, 1, 0, NN, 672, flags);

    // pool + fused ffn (all f32)
    graph_starts<<<cdiv(NN, 256), 256, 0, stream>>>(b32, gstart, NN, G);
    pool_nodes<<<G, 256, 0, stream>>>(hn, gstart, Apool);
    ffn_fused<<<G / 8, 256, 0, stream>>>(Apool, d_in[10], d_in[11], d_in[12], d_in[13], d_out, flags);
}

// Round 17
// 1711.357 us; speedup vs baseline: 1.3493x; 1.3493x over previous
//
#include <hip/hip_runtime.h>

typedef __bf16 bf16x8 __attribute__((ext_vector_type(8)));
typedef float  f32x4  __attribute__((ext_vector_type(4)));

#define E_EDGES 100000
#define N_NODES 25000
#define N_GRAPHS 2048
#define HID 512
#define CAP 32

__device__ __forceinline__ void gload_lds16(const void* g, void* l) {
    __builtin_amdgcn_global_load_lds(
        (const __attribute__((address_space(1))) void*)g,
        (__attribute__((address_space(3))) void*)l, 16, 0, 0);
}

__device__ __forceinline__ __bf16 rtne(float x) {
    union { unsigned short s; __bf16 b; } u;
    unsigned v = __float_as_uint(x);
    u.s = (unsigned short)((v + 0x7FFF + ((v >> 16) & 1)) >> 16);
    return u.b;
}

__device__ __forceinline__ void split2(float x, __bf16& hi, __bf16& lo) {
    hi = rtne(x);
    lo = rtne(x - (float)hi);
}

__device__ __forceinline__ float ldf(const void* p, long i, int f32) {
    return f32 ? ((const float*)p)[i] : (float)(((const __bf16*)p)[i]);
}

// flags[0]=1 if float inputs are f32 (else bf16); flags[1]=1 if int inputs are i64
__global__ void probe_dtypes(const unsigned* __restrict__ xr, const unsigned* __restrict__ eir,
                             int* __restrict__ flags)
{
    __shared__ int cfp, ci;
    if (threadIdx.x == 0) { cfp = 0; ci = 0; }
    __syncthreads();
    int lc = 0;
    for (int i = threadIdx.x; i < 1024; i += 256) {
        unsigned elo = (xr[i] >> 7) & 0xFFu;
        if (elo > 140u) lc++;
    }
    atomicAdd(&cfp, lc);
    int ln = 0;
    for (int i = threadIdx.x; i < 512; i += 256) {
        if (eir[2 * i + 1] != 0u) ln++;
    }
    atomicAdd(&ci, ln);
    __syncthreads();
    if (threadIdx.x == 0) {
        flags[0] = (cfp > 100) ? 1 : 0;
        flags[1] = (ci < 256) ? 1 : 0;
    }
}

__global__ void to_int32(const void* __restrict__ src, int* __restrict__ dst, long n,
                         const int* __restrict__ flags)
{
    long i = (long)blockIdx.x * 256 + threadIdx.x;
    if (i >= n) return;
    dst[i] = flags[1] ? (int)((const long long*)src)[i] : ((const int*)src)[i];
}

// Tiled transpose+split: WThi/WTlo[n,k] = split(W[krow0 + z*512 + k, n]), zero-pad to Kpad.
// gridDim.z batches layers (dst advances by N*Kpad per z).
__global__ __launch_bounds__(256) void split_transpose_t(
    const void* __restrict__ W, __bf16* __restrict__ Whi, __bf16* __restrict__ Wlo,
    int Ksrc, int N, int Kpad, int krow0, const int* __restrict__ flags)
{
    __shared__ float tile[64][65];
    const int z = blockIdx.z;
    const int nb = blockIdx.x * 64;
    const int kb = blockIdx.y * 64;
    const int f32m = flags[0];
    const int lx = threadIdx.x & 63;
    const size_t dsto = (size_t)z * N * Kpad;
    const int kro = krow0 + z * 512;

    for (int rr = threadIdx.x >> 6; rr < 64; rr += 4) {
        const int k = kb + rr;
        const int n = nb + lx;
        float v = 0.f;
        if (k < Ksrc && n < N) v = ldf(W, (size_t)(kro + k) * N + n, f32m);
        tile[rr][lx] = v;
    }
    __syncthreads();
    for (int rr = threadIdx.x >> 6; rr < 64; rr += 4) {
        const int n = nb + rr;
        const int k = kb + lx;
        if (n < N && k < Kpad) {
            __bf16 hi, lo; split2(tile[lx][rr], hi, lo);
            Whi[dsto + (size_t)n * Kpad + k] = hi;
            Wlo[dsto + (size_t)n * Kpad + k] = lo;
        }
    }
}

// A_init[e,0:160] = [x[row[e],0:133], ea[e,0:14], 0] -> hi/lo; one thread per 8-f chunk
__global__ void build_Ainit_split8(const void* __restrict__ x, const void* __restrict__ ea,
                                   const int* __restrict__ row, __bf16* __restrict__ Ah,
                                   __bf16* __restrict__ Al, const int* __restrict__ flags)
{
    long idx = (long)blockIdx.x * 256 + threadIdx.x;
    if (idx >= (long)E_EDGES * 20) return;
    const int e = (int)(idx / 20), c = (int)(idx % 20);
    const int f0 = c * 8;
    const int f32m = flags[0];
    const int r = row[e];
    bf16x8 oh, ol;
    #pragma unroll
    for (int j = 0; j < 8; ++j) {
        const int f = f0 + j;
        float v = 0.f;
        if (f < 133)      v = ldf(x, (size_t)r * 133 + f, f32m);
        else if (f < 147) v = ldf(ea, (size_t)e * 14 + (f - 133), f32m);
        __bf16 hi, lo; split2(v, hi, lo);
        oh[j] = hi; ol[j] = lo;
    }
    *(bf16x8*)(Ah + (size_t)e * 160 + f0) = oh;
    *(bf16x8*)(Al + (size_t)e * 160 + f0) = ol;
}

// A_e2n[n,0:672] = [x[n,0:133], s_f32[n,0:512], 0] -> hi/lo; one thread per 8-f chunk
__global__ void build_Ae2n_split8(const void* __restrict__ x, const float* __restrict__ s,
                                  __bf16* __restrict__ Ah, __bf16* __restrict__ Al,
                                  const int* __restrict__ flags)
{
    long idx = (long)blockIdx.x * 256 + threadIdx.x;
    if (idx >= (long)N_NODES * 84) return;
    const int n = (int)(idx / 84), c = (int)(idx % 84);
    const int f0 = c * 8;
    const int f32m = flags[0];
    bf16x8 oh, ol;
    #pragma unroll
    for (int j = 0; j < 8; ++j) {
        const int f = f0 + j;
        float v = 0.f;
        if (f < 133)      v = ldf(x, (size_t)n * 133 + f, f32m);
        else if (f < 645) v = s[(size_t)n * HID + (f - 133)];
        __bf16 hi, lo; split2(v, hi, lo);
        oh[j] = hi; ol[j] = lo;
    }
    *(bf16x8*)(Ah + (size_t)n * 672 + f0) = oh;
    *(bf16x8*)(Al + (size_t)n * 672 + f0) = ol;
}

// Wide split-precision GEMM: C[M,512] = relu(A @ BT^T + bias), 3-term MFMA.
__global__ __launch_bounds__(1024) void gemm3w(
    const __bf16* __restrict__ Ah, const __bf16* __restrict__ Al,
    const __bf16* __restrict__ Bh, const __bf16* __restrict__ Bl,
    const void* __restrict__ bias,
    void* __restrict__ C, int out_f32, int kmaj, int M, int K, const int* __restrict__ flags)
{
    __shared__ __bf16 lAh[128 * 32];
    __shared__ __bf16 lAl[128 * 32];
    __shared__ __bf16 lBh[512 * 32];

    const int m0 = blockIdx.x * 128;
    const int tid = threadIdx.x;
    const int w = tid >> 6;
    const int lane = tid & 63;

    const int ac = tid & 511;
    int arow = m0 + (ac >> 2); if (arow >= M) arow = M - 1;
    const int akc = (ac & 3) << 3;
    const __bf16* Asrc = (tid < 512) ? Ah : Al;
    const size_t ag = (size_t)arow * K + akc;
    __bf16* aw = ((tid < 512) ? lAh : lAl) + (ac >> 2) * 32 + akc;

    const size_t bg0 = (size_t)(tid >> 2) * K + ((tid & 3) << 3);
    const size_t bg1 = (size_t)((tid + 1024) >> 2) * K + (((tid + 1024) & 3) << 3);
    __bf16* wB0 = lBh + (size_t)tid * 8;
    __bf16* wB1 = lBh + (size_t)(tid + 1024) * 8;

    const int mh = (w >> 3) * 64;
    const int nq = (w & 7) * 64;
    const int c16 = lane & 15;
    const int quad = lane >> 4;

    const __bf16* blp = Bl + (size_t)(nq + c16) * K + quad * 8;

    f32x4 acc[4][4] = {};

    for (int k0 = 0; k0 < K; k0 += 32) {
        gload_lds16(Asrc + ag + k0, aw);
        gload_lds16(Bh + bg0 + k0, wB0);
        gload_lds16(Bh + bg1 + k0, wB1);
        __syncthreads();

        bf16x8 bl[4];
        #pragma unroll
        for (int j = 0; j < 4; ++j)
            bl[j] = *(const bf16x8*)(blp + (size_t)(j * 16) * K + k0);

        bf16x8 ah[4], al[4];
        #pragma unroll
        for (int i = 0; i < 4; ++i) {
            ah[i] = *(const bf16x8*)(lAh + (mh + i * 16 + c16) * 32 + quad * 8);
            al[i] = *(const bf16x8*)(lAl + (mh + i * 16 + c16) * 32 + quad * 8);
        }
        #pragma unroll
        for (int j = 0; j < 4; ++j) {
            bf16x8 bh = *(const bf16x8*)(lBh + (nq + j * 16 + c16) * 32 + quad * 8);
            #pragma unroll
            for (int i = 0; i < 4; ++i) {
                acc[i][j] = __builtin_amdgcn_mfma_f32_16x16x32_bf16(ah[i], bh, acc[i][j], 0, 0, 0);
                acc[i][j] = __builtin_amdgcn_mfma_f32_16x16x32_bf16(al[i], bh, acc[i][j], 0, 0, 0);
                acc[i][j] = __builtin_amdgcn_mfma_f32_16x16x32_bf16(ah[i], bl[j], acc[i][j], 0, 0, 0);
            }
        }
        __syncthreads();
    }

    const int f32 = flags[0];
    const size_t kstride = (size_t)M * 32;
    #pragma unroll
    for (int j = 0; j < 4; ++j) {
        const int gcol = nq + j * 16 + c16;
        const float bv = ldf(bias, gcol, f32);
        #pragma unroll
        for (int i = 0; i < 4; ++i) {
            const int growb = m0 + mh + i * 16 + quad * 4;
            #pragma unroll
            for (int rr = 0; rr < 4; ++rr) {
                const int grow = growb + rr;
                if (grow < M) {
                    float v = acc[i][j][rr] + bv;
                    v = v > 0.f ? v : 0.f;
                    if (out_f32)   ((float*)C)[(size_t)grow * HID + gcol] = v;
                    else if (kmaj) ((__bf16*)C)[(size_t)(gcol >> 5) * kstride + (size_t)grow * 32 + (gcol & 31)] = rtne(v);
                    else           ((__bf16*)C)[(size_t)grow * HID + gcol] = rtne(v);
                }
            }
        }
    }
}

// DMPNN conv (r12 structure, 2-TERM: mh@(Bh+Bl)) — best known (276us plateau).
__global__ __launch_bounds__(1024) void conv3(
    const __bf16* __restrict__ abuf, const __bf16* hsrc,
    const int* __restrict__ row, const __bf16* __restrict__ Bh,
    const __bf16* __restrict__ Bl, const void* __restrict__ bias, int bias_off,
    const __bf16* __restrict__ res, __bf16* hdst, int M, const int* __restrict__ flags)
{
    __shared__ __bf16 lAh[128 * 32];   // 8KB
    __shared__ __bf16 lBh[512 * 32];   // 32KB

    const int m0 = blockIdx.x * 128;
    const int tid = threadIdx.x;
    const int w = tid >> 6;
    const int lane = tid & 63;
    const size_t kstride = (size_t)M * 32;

    const bool astage = (tid < 512);
    const int arow = (tid & 511) >> 2;
    const int akc = (tid & 3) << 3;
    int e = m0 + arow; if (e >= M) e = M - 1;
    const int rn = row[e];
    const int vv = e ^ 1;
    const __bf16* ap = abuf + (size_t)rn * HID + akc;
    const __bf16* hp = hsrc + (size_t)vv * 32 + akc;
    __bf16* wAh = lAh + arow * 32 + akc;

    const size_t bg0 = (size_t)(tid >> 2) * HID + ((tid & 3) << 3);
    const size_t bg1 = (size_t)((tid + 1024) >> 2) * HID + (((tid + 1024) & 3) << 3);
    __bf16* wB0 = lBh + (size_t)tid * 8;
    __bf16* wB1 = lBh + (size_t)(tid + 1024) * 8;

    const int mh = (w >> 3) * 64;
    const int nq = (w & 7) * 64;
    const int c16 = lane & 15;
    const int quad = lane >> 4;

    const __bf16* blp = Bl + (size_t)(nq + c16) * HID + quad * 8;

    f32x4 acc[4][4] = {};

    bf16x8 av, hv;
    if (astage) {
        av = *(const bf16x8*)(ap);
        hv = *(const bf16x8*)(hp);
    }

    for (int k0 = 0; k0 < HID; k0 += 32) {
        const int kb = k0 >> 5;
        if (astage) {
            bf16x8 mh8;
            #pragma unroll
            for (int j = 0; j < 8; ++j)
                mh8[j] = rtne((float)av[j] - (float)hv[j]);
            *(bf16x8*)wAh = mh8;
        }
        gload_lds16(Bh + bg0 + k0, wB0);
        gload_lds16(Bh + bg1 + k0, wB1);
        if (astage && k0 + 32 < HID) {
            av = *(const bf16x8*)(ap + k0 + 32);
            hv = *(const bf16x8*)(hp + (size_t)(kb + 1) * kstride);
        }
        __syncthreads();

        bf16x8 bl[4];
        #pragma unroll
        for (int j = 0; j < 4; ++j)
            bl[j] = *(const bf16x8*)(blp + (size_t)(j * 16) * HID + k0);

        bf16x8 ah[4];
        #pragma unroll
        for (int i = 0; i < 4; ++i)
            ah[i] = *(const bf16x8*)(lAh + (mh + i * 16 + c16) * 32 + quad * 8);

        #pragma unroll
        for (int j = 0; j < 4; ++j) {
            bf16x8 bh = *(const bf16x8*)(lBh + (nq + j * 16 + c16) * 32 + quad * 8);
            #pragma unroll
            for (int i = 0; i < 4; ++i) {
                acc[i][j] = __builtin_amdgcn_mfma_f32_16x16x32_bf16(ah[i], bh, acc[i][j], 0, 0, 0);
                acc[i][j] = __builtin_amdgcn_mfma_f32_16x16x32_bf16(ah[i], bl[j], acc[i][j], 0, 0, 0);
            }
        }
        __syncthreads();
    }

    const int f32 = flags[0];
    #pragma unroll
    for (int j = 0; j < 4; ++j) {
        const int gcol = nq + j * 16 + c16;
        const float bv = ldf(bias, bias_off + gcol, f32);
        const size_t cb = (size_t)(gcol >> 5) * kstride + (gcol & 31);
        #pragma unroll
        for (int i = 0; i < 4; ++i) {
            const int growb = m0 + mh + i * 16 + quad * 4;
            #pragma unroll
            for (int rr = 0; rr < 4; ++rr) {
                const int grow = growb + rr;
                if (grow < M) {
                    const size_t idx = cb + (size_t)grow * 32;
                    float vcur = acc[i][j][rr] + bv + (float)res[idx];
                    vcur = vcur > 0.f ? vcur : 0.f;
                    hdst[idx] = rtne(vcur);
                }
            }
        }
    }
}

__global__ void bucket_build(const int* __restrict__ col, int* __restrict__ counts,
                             int* __restrict__ buckets, int E)
{
    int e = blockIdx.x * 256 + threadIdx.x;
    if (e >= E) return;
    int c = col[e];
    int p = atomicAdd(&counts[c], 1);
    if (p < CAP) buckets[(size_t)c * CAP + p] = e;
}

// Vectorized segsum: one thread per (node, 8-feature chunk); h K-MAJOR [16][E][32].
__global__ __launch_bounds__(256) void segsum8(
    const __bf16* __restrict__ h, const int* __restrict__ counts,
    const int* __restrict__ buckets, __bf16* __restrict__ abf,
    float* __restrict__ af32)
{
    const int nid = blockIdx.x * 4 + (threadIdx.x >> 6);
    const int fc = threadIdx.x & 63;
    if (nid >= N_NODES) return;
    const int kb = fc >> 2;
    const int off = (fc & 3) << 3;
    const size_t base = (size_t)kb * ((size_t)E_EDGES * 32) + off;
    int cnt = counts[nid]; if (cnt > CAP) cnt = CAP;
    const int* bl = buckets + (size_t)nid * CAP;
    float s[8] = {0.f, 0.f, 0.f, 0.f, 0.f, 0.f, 0.f, 0.f};
    for (int i = 0; i < cnt; ++i) {
        const int e = bl[i];
        bf16x8 v = *(const bf16x8*)(h + base + (size_t)e * 32);
        #pragma unroll
        for (int j = 0; j < 8; ++j) s[j] += (float)v[j];
    }
    if (af32) {
        f32x4* out = (f32x4*)(af32 + (size_t)nid * HID + fc * 8);
        out[0] = f32x4{s[0], s[1], s[2], s[3]};
        out[1] = f32x4{s[4], s[5], s[6], s[7]};
    } else {
        bf16x8 o;
        #pragma unroll
        for (int j = 0; j < 8; ++j) o[j] = rtne(s[j]);
        *(bf16x8*)(abf + (size_t)nid * HID + fc * 8) = o;
    }
}

__global__ void graph_starts(const int* __restrict__ batch, int* __restrict__ gstart, int N, int G)
{
    int n = blockIdx.x * 256 + threadIdx.x;
    if (n >= N) return;
    int b = batch[n];
    if (n == 0) {
        for (int g = 0; g <= b; ++g) gstart[g] = 0;
    } else {
        int pb = batch[n - 1];
        for (int g = pb + 1; g <= b; ++g) gstart[g] = n;
    }
    if (n == N - 1) {
        for (int g = b + 1; g <= G; ++g) gstart[g] = N;
    }
}

__global__ void pool_nodes(const float* __restrict__ hn, const int* __restrict__ gstart,
                           float* __restrict__ Apool)
{
    int g = blockIdx.x;
    int s = gstart[g], e = gstart[g + 1];
    for (int f = threadIdx.x; f < HID; f += 256) {
        float acc = 0.f;
        for (int n = s; n < e; ++n) acc += hn[(size_t)n * HID + f];
        Apool[(size_t)g * HID + f] = acc;
    }
}

// fused ffn: per block 8 graphs; t = relu(Apool@W1+b1); out = t@W2 + b2 (all f32)
__global__ __launch_bounds__(256) void ffn_fused(
    const float* __restrict__ Apool, const void* __restrict__ W1,
    const void* __restrict__ b1, const void* __restrict__ W2,
    const void* __restrict__ b2v, void* __restrict__ outv,
    const int* __restrict__ flags)
{
    __shared__ float sA[8][512];
    __shared__ float t[8][512];
    __shared__ float sW2[512];
    __shared__ float red[4];
    const int tid = threadIdx.x;
    const int g0 = blockIdx.x * 8;
    const int f32 = flags[0];

    for (int i = tid; i < 4096; i += 256)
        sA[i >> 9][i & 511] = Apool[(size_t)g0 * 512 + i];
    for (int n = tid; n < 512; n += 256)
        sW2[n] = ldf(W2, n, f32);
    __syncthreads();

    {
        float acc0[8], acc1[8];
        const float bb0 = ldf(b1, tid, f32);
        const float bb1 = ldf(b1, tid + 256, f32);
        #pragma unroll
        for (int gi = 0; gi < 8; ++gi) { acc0[gi] = bb0; acc1[gi] = bb1; }
        if (f32) {
            const float* Wf = (const float*)W1;
            for (int k = 0; k < 512; ++k) {
                float w0 = Wf[(size_t)k * 512 + tid];
                float w1 = Wf[(size_t)k * 512 + tid + 256];
                #pragma unroll
                for (int gi = 0; gi < 8; ++gi) {
                    float a = sA[gi][k];
                    acc0[gi] += a * w0;
                    acc1[gi] += a * w1;
                }
            }
        } else {
            const __bf16* Wb = (const __bf16*)W1;
            for (int k = 0; k < 512; ++k) {
                float w0 = (float)Wb[(size_t)k * 512 + tid];
                float w1 = (float)Wb[(size_t)k * 512 + tid + 256];
                #pragma unroll
                for (int gi = 0; gi < 8; ++gi) {
                    float a = sA[gi][k];
                    acc0[gi] += a * w0;
                    acc1[gi] += a * w1;
                }
            }
        }
        #pragma unroll
        for (int gi = 0; gi < 8; ++gi) {
            t[gi][tid]       = acc0[gi] > 0.f ? acc0[gi] : 0.f;
            t[gi][tid + 256] = acc1[gi] > 0.f ? acc1[gi] : 0.f;
        }
    }
    __syncthreads();

    const int lane = tid & 63;
    const int w = tid >> 6;
    const float b2 = ldf(b2v, 0, f32);
    for (int gi = 0; gi < 8; ++gi) {
        float p = t[gi][tid] * sW2[tid] + t[gi][tid + 256] * sW2[tid + 256];
        for (int o = 32; o; o >>= 1) p += __shfl_down(p, o, 64);
        if (lane == 0) red[w] = p;
        __syncthreads();
        if (tid == 0) {
            float r = red[0] + red[1] + red[2] + red[3] + b2;
            if (f32) ((float*)outv)[g0 + gi] = r;
            else     ((__bf16*)outv)[g0 + gi] = rtne(r);
        }
        __syncthreads();
    }
}

extern "C" void kernel_launch(void* const* d_in, const int* in_sizes, int n_in,
                              void* d_out, int out_size, void* d_ws, size_t ws_size,
                              hipStream_t stream)
{
    const int E = E_EDGES, NN = N_NODES, G = N_GRAPHS;

    char* wsp = (char*)d_ws;
    size_t off = 0;
    auto carve = [&](size_t bytes) -> void* {
        void* p = wsp + off;
        off += (bytes + 511) & ~(size_t)511;
        return p;
    };

    __bf16* h0    = (__bf16*)carve((size_t)E * HID * 2);   // k-major [16][E][32]
    __bf16* h     = (__bf16*)carve((size_t)E * HID * 2);   // k-major (also Ainit/Ae2n scratch)
    __bf16* abuf  = (__bf16*)carve((size_t)NN * HID * 2);  // row-major
    float*  Apool = (float*) carve((size_t)G * HID * 4);
    __bf16* WTih  = (__bf16*)carve((size_t)512 * 160 * 2);
    __bf16* WTil  = (__bf16*)carve((size_t)512 * 160 * 2);
    __bf16* WTch  = (__bf16*)carve((size_t)4 * 512 * 512 * 2);
    __bf16* WTcl  = (__bf16*)carve((size_t)4 * 512 * 512 * 2);
    __bf16* WTqh  = (__bf16*)carve((size_t)512 * 672 * 2);
    __bf16* WTql  = (__bf16*)carve((size_t)512 * 672 * 2);
    int*    ei32  = (int*)   carve((size_t)2 * E * 4);
    int*    b32   = (int*)   carve((size_t)NN * 4);
    int*    counts= (int*)   carve((size_t)NN * 4);
    int*    bucket= (int*)   carve((size_t)NN * CAP * 4);
    int*    gstart= (int*)   carve((size_t)(G + 1) * 4);
    int*    flags = (int*)   carve(2 * 4);

    // aliases into provably-dead regions
    __bf16* Aih = h;                              // E*160 bf16 (32 MB)
    __bf16* Ail = h + (size_t)E * 160;            // 32 MB; h dead until conv layer-1 output
    __bf16* Aqh = h;                              // NN*672 (33.6 MB)
    __bf16* Aql = h + (size_t)NN * 672;           // h dead after final segsum
    float*  hn   = (float*)h0;                    // NN*512 f32; h0 dead after conv4
    float*  sfin = (float*)((char*)h0 + (size_t)NN * HID * 4);  // NN*512 f32 (row-major)

    if (off > ws_size) {  // clean fail instead of faulting
        hipMemsetAsync(d_out, 0, (size_t)out_size * 4, stream);
        return;
    }

    auto cdiv = [](long a, long b) { return (int)((a + b - 1) / b); };

    probe_dtypes<<<1, 256, 0, stream>>>((const unsigned*)d_in[0], (const unsigned*)d_in[1], flags);
    to_int32<<<cdiv((long)2 * E, 256), 256, 0, stream>>>(d_in[1], ei32, (long)2 * E, flags);
    to_int32<<<cdiv(NN, 256), 256, 0, stream>>>(d_in[3], b32, NN, flags);

    const int* row = ei32;
    const int* col = ei32 + E;

    hipMemsetAsync(counts, 0, (size_t)NN * 4, stream);

    split_transpose_t<<<dim3(8, 3, 1), 256, 0, stream>>>(d_in[4], WTih, WTil, 147, 512, 160, 0, flags);
    split_transpose_t<<<dim3(8, 8, 4), 256, 0, stream>>>(d_in[6], WTch, WTcl, 512, 512, 512, 0, flags);
    split_transpose_t<<<dim3(8, 11, 1), 256, 0, stream>>>(d_in[8], WTqh, WTql, 645, 512, 672, 0, flags);

    bucket_build<<<cdiv(E, 256), 256, 0, stream>>>(col, counts, bucket, E);

    // edge init: h0 = relu([x[row], ea] @ W_ei + b_ei) -> k-major  (wide 3-term GEMM)
    build_Ainit_split8<<<cdiv((long)E * 20, 256), 256, 0, stream>>>(d_in[0], d_in[2], row, Aih, Ail, flags);
    gemm3w<<<cdiv(E, 128), 1024, 0, stream>>>(Aih, Ail, WTih, WTil, d_in[5], h0, 0, 1, E, 160, flags);

    // DMPNN layers (layer 1: h0 -> h; layers 2-4 in-place h -> h), all k-major
    const __bf16* hcur = h0;
    for (int l = 0; l < 4; ++l) {
        segsum8<<<cdiv(NN, 4), 256, 0, stream>>>(hcur, counts, bucket, abuf, nullptr);
        conv3<<<cdiv(E, 128), 1024, 0, stream>>>(
            abuf, hcur, row, WTch + (size_t)l * 512 * 512, WTcl + (size_t)l * 512 * 512,
            d_in[7], l * 512, h0, h, E, flags);
        hcur = h;
    }

    // final aggregation (f32, row-major out) + e2n (wide 3-term GEMM, f32 row-major out)
    segsum8<<<cdiv(NN, 4), 256, 0, stream>>>(hcur, counts, bucket, nullptr, sfin);
    build_Ae2n_split8<<<cdiv((long)NN * 84, 256), 256, 0, stream>>>(d_in[0], sfin, Aqh, Aql, flags);
    gemm3w<<<cdiv(NN, 128), 1024, 0, stream>>>(Aqh, Aql, WTqh, WTql, d_in[9], hn, 1, 0, NN, 672, flags);

    // pool + fused ffn (all f32)
    graph_starts<<<cdiv(NN, 256), 256, 0, stream>>>(b32, gstart, NN, G);
    pool_nodes<<<G, 256, 0, stream>>>(hn, gstart, Apool);
    ffn_fused<<<G / 8, 256, 0, stream>>>(Apool, d_in[10], d_in[11], d_in[12], d_in[13], d_out, flags);
}